// Round 1
// baseline (325.498 us; speedup 1.0000x reference)
//
#include <hip/hip_runtime.h>
#include <math.h>

#define BATCH 32
#define DIM   4096
#define CLEN  4096
#define HD    128
#define NKV   8
#define NHEAD 32
#define QKVN  6144          // (32 + 2*8) * 128
#define KSEG  128           // K per gemm block
#define NSEG  32            // 4096 / 128
#define GN    128           // N per gemm block
#define TCHUNK 512
#define NCH    8            // 4096 / 512
#define TTILE  32

// ---------------- helpers ----------------
__device__ __forceinline__ void gload_lds16(const float* g, float* l) {
  __builtin_amdgcn_global_load_lds(
      (const __attribute__((address_space(1))) void*)g,
      (__attribute__((address_space(3))) void*)l, 16, 0, 0);
}

template <int CTRL>
__device__ __forceinline__ float dpp_add(float x) {
  int y = __builtin_amdgcn_update_dpp(0, __float_as_int(x), CTRL, 0xF, 0xF, true);
  return x + __int_as_float(y);
}

// sum across the 32 lanes of each half-wave (masks 1,2,4,8 via DPP, 16 via swizzle)
__device__ __forceinline__ float half_reduce(float s) {
  s = dpp_add<0xB1>(s);    // quad_perm xor1
  s = dpp_add<0x4E>(s);    // quad_perm xor2
  s = dpp_add<0x124>(s);   // row_ror:4
  s = dpp_add<0x128>(s);   // row_ror:8
  s += __int_as_float(__builtin_amdgcn_ds_swizzle(__float_as_int(s), 0x401F)); // xor16
  return s;
}

// ---------------- skinny GEMM partial: part[seg][b][n] = sum_{k in seg} X[b][k]*W[n][k]
__global__ __launch_bounds__(256)
void gemm_partial(const float* __restrict__ X, const float* __restrict__ W,
                  float* __restrict__ part, const int N) {
  __shared__ float xs[KSEG][BATCH + 4];   // [k][b]
  __shared__ float wl[KSEG][GN + 4];      // [k][n]
  const int tid = threadIdx.x;
  const int n0  = blockIdx.x * GN;
  const int k0  = blockIdx.y * KSEG;
  {
    const int c = tid & 31;   // float4 column (128k = 32 f4)
    const int r = tid >> 5;   // 0..7
#pragma unroll
    for (int p = 0; p < 4; ++p) {
      const int b = p * 8 + r;
      const float4 v = *(const float4*)(X + (size_t)b * DIM + k0 + c * 4);
      const int k = c * 4;
      xs[k][b] = v.x; xs[k + 1][b] = v.y; xs[k + 2][b] = v.z; xs[k + 3][b] = v.w;
    }
#pragma unroll
    for (int p = 0; p < 16; ++p) {
      const int n = p * 8 + r;
      const float4 v = *(const float4*)(W + (size_t)(n0 + n) * DIM + k0 + c * 4);
      const int k = c * 4;
      wl[k][n] = v.x; wl[k + 1][n] = v.y; wl[k + 2][n] = v.z; wl[k + 3][n] = v.w;
    }
  }
  __syncthreads();
  const int bq = (tid & 7) << 2;
  const int nq = (tid >> 3) << 2;
  float a00=0,a01=0,a02=0,a03=0, a10=0,a11=0,a12=0,a13=0;
  float a20=0,a21=0,a22=0,a23=0, a30=0,a31=0,a32=0,a33=0;
#pragma unroll 8
  for (int k = 0; k < KSEG; ++k) {
    const float4 xv = *(const float4*)&xs[k][bq];
    const float4 wv = *(const float4*)&wl[k][nq];
    a00 += xv.x * wv.x; a01 += xv.x * wv.y; a02 += xv.x * wv.z; a03 += xv.x * wv.w;
    a10 += xv.y * wv.x; a11 += xv.y * wv.y; a12 += xv.y * wv.z; a13 += xv.y * wv.w;
    a20 += xv.z * wv.x; a21 += xv.z * wv.y; a22 += xv.z * wv.z; a23 += xv.z * wv.w;
    a30 += xv.w * wv.x; a31 += xv.w * wv.y; a32 += xv.w * wv.z; a33 += xv.w * wv.w;
  }
  float* o0 = part + ((size_t)blockIdx.y * BATCH + bq + 0) * N + n0 + nq;
  float* o1 = part + ((size_t)blockIdx.y * BATCH + bq + 1) * N + n0 + nq;
  float* o2 = part + ((size_t)blockIdx.y * BATCH + bq + 2) * N + n0 + nq;
  float* o3 = part + ((size_t)blockIdx.y * BATCH + bq + 3) * N + n0 + nq;
  *(float4*)o0 = make_float4(a00, a01, a02, a03);
  *(float4*)o1 = make_float4(a10, a11, a12, a13);
  *(float4*)o2 = make_float4(a20, a21, a22, a23);
  *(float4*)o3 = make_float4(a30, a31, a32, a33);
}

// ---------------- qkv combine + RoPE ----------------
__global__ __launch_bounds__(256)
void qkv_combine(const float* __restrict__ part, const int* __restrict__ ctxp,
                 float* __restrict__ qw, float* __restrict__ kn, float* __restrict__ vn) {
  const int idx = blockIdx.x * 256 + threadIdx.x;  // pair index: 32*3072
  const int b  = idx / (QKVN / 2);
  const int c  = idx % (QKVN / 2);
  const int n0 = c * 2;
  float v0 = 0.f, v1 = 0.f;
#pragma unroll
  for (int s = 0; s < NSEG; ++s) {
    const float2 pv = *(const float2*)(part + ((size_t)s * BATCH + b) * QKVN + n0);
    v0 += pv.x; v1 += pv.y;
  }
  const float pos = (float)ctxp[0];
  const float L2T_OVER_64 = 0.20762050593045952f;  // log2(10000)/64
  if (n0 < DIM) {
    const int i = (n0 & 127) >> 1;
    const float fr = exp2f(-(float)i * L2T_OVER_64);
    float sn, cs; sincosf(pos * fr, &sn, &cs);
    qw[(size_t)b * DIM + n0]     = v0 * cs - v1 * sn;
    qw[(size_t)b * DIM + n0 + 1] = v0 * sn + v1 * cs;
  } else if (n0 < DIM + NKV * HD) {
    const int nk = n0 - DIM;
    const int i = (nk & 127) >> 1;
    const float fr = exp2f(-(float)i * L2T_OVER_64);
    float sn, cs; sincosf(pos * fr, &sn, &cs);
    kn[(size_t)b * (NKV * HD) + nk]     = v0 * cs - v1 * sn;
    kn[(size_t)b * (NKV * HD) + nk + 1] = v0 * sn + v1 * cs;
  } else {
    const int nv = n0 - DIM - NKV * HD;
    vn[(size_t)b * (NKV * HD) + nv]     = v0;
    vn[(size_t)b * (NKV * HD) + nv + 1] = v1;
  }
}

// ---------------- flash-decode partial ----------------
template <bool MASKED>
__device__ __forceinline__ void attn_tile(const float* kls, const float* vls,
    const float4 q4, const int t0, const int T, const int half, const int dq,
    float& m, float& ll, float4& acc) {
#pragma unroll
  for (int u = 0; u < TTILE / 2; ++u) {
    const float4 k4 = *(const float4*)&kls[(u * 2 + half) * HD + dq];
    float s = k4.x * q4.x + k4.y * q4.y + k4.z * q4.z + k4.w * q4.w;
    s = half_reduce(s);
    if (MASKED) { if (t0 + u * 2 + half >= T) s = -INFINITY; }
    if (s > m) {
      const float rs = __expf(m - s);
      acc.x *= rs; acc.y *= rs; acc.z *= rs; acc.w *= rs;
      ll *= rs; m = s;
    }
    const float p = __expf(s - m);
    ll += p;
    const float4 v4 = *(const float4*)&vls[(u * 2 + half) * HD + dq];
    acc.x += p * v4.x; acc.y += p * v4.y; acc.z += p * v4.z; acc.w += p * v4.w;
  }
}

__global__ __launch_bounds__(256)
void attn_partial(const float* __restrict__ qw, const float* __restrict__ knew,
                  const float* __restrict__ vnew, const float* __restrict__ ck,
                  const float* __restrict__ cv, const int* __restrict__ ctxp,
                  float* __restrict__ opart, float* __restrict__ mlp) {
  __shared__ float kls[TTILE * HD];
  __shared__ float vls[TTILE * HD];
  const int bg    = blockIdx.x;        // b*8 + g
  const int chunk = blockIdx.y;
  const int b = bg >> 3, g = bg & 7;
  const int wid  = threadIdx.x >> 6;   // head within group
  const int lane = threadIdx.x & 63;
  const int half = lane >> 5;
  const int dq   = (lane & 31) << 2;
  const int T    = ctxp[0] + 1;
  const int ctx  = T - 1;
  const int c0   = chunk * TCHUNK;

  float4 q4 = *(const float4*)(qw + ((size_t)b * NHEAD + (g * 4 + wid)) * HD + dq);
  const float sc = 0.08838834764831845f;  // 1/sqrt(128)
  q4.x *= sc; q4.y *= sc; q4.z *= sc; q4.w *= sc;

  const float* ckb = ck + ((size_t)b * CLEN * NKV + g) * HD;
  const float* cvb = cv + ((size_t)b * CLEN * NKV + g) * HD;
  const float* knr = knew + ((size_t)b * NKV + g) * HD;
  const float* vnr = vnew + ((size_t)b * NKV + g) * HD;

  float m = -INFINITY, ll = 0.f;
  float4 acc = make_float4(0.f, 0.f, 0.f, 0.f);

  for (int tile = 0; tile < TCHUNK / TTILE; ++tile) {
    const int t0 = c0 + tile * TTILE;
    if (tile) __syncthreads();         // previous compute done before overwrite
    if (t0 < T) {                      // block-uniform
#pragma unroll
      for (int i = 0; i < 4; ++i) {
        const int tr = t0 + wid * 8 + i * 2 + half;   // this lane's source row
        const float* ksrc = ((tr == ctx) ? knr : (ckb + (size_t)tr * (NKV * HD))) + dq;
        const float* vsrc = ((tr == ctx) ? vnr : (cvb + (size_t)tr * (NKV * HD))) + dq;
        gload_lds16(ksrc, &kls[(wid * 8 + i * 2) * HD]);
        gload_lds16(vsrc, &vls[(wid * 8 + i * 2) * HD]);
      }
    }
    __syncthreads();                   // staging complete (vmcnt drained)
    if (t0 + TTILE <= T)      attn_tile<false>(kls, vls, q4, t0, T, half, dq, m, ll, acc);
    else if (t0 < T)          attn_tile<true >(kls, vls, q4, t0, T, half, dq, m, ll, acc);
  }

  const int pi = bg * 4 + wid;                         // 0..1023
  const size_t slot = (size_t)pi * (NCH * 2) + chunk * 2 + half;
  *(float4*)(opart + slot * HD + dq) = acc;
  if ((lane & 31) == 0) { mlp[slot * 2] = m; mlp[slot * 2 + 1] = ll; }
}

// ---------------- flash combine ----------------
__global__ __launch_bounds__(128)
void attn_combine(const float* __restrict__ opart, const float* __restrict__ mlp,
                  float* __restrict__ ow) {
  const int p = blockIdx.x;      // 0..1023 = b*32 + g*4 + h
  const int d = threadIdx.x;     // 0..127
  float M = -INFINITY;
#pragma unroll
  for (int c = 0; c < NCH * 2; ++c) M = fmaxf(M, mlp[((size_t)p * (NCH * 2) + c) * 2]);
  float L = 0.f, O = 0.f;
#pragma unroll
  for (int c = 0; c < NCH * 2; ++c) {
    const float mi = mlp[((size_t)p * (NCH * 2) + c) * 2];
    if (mi > -INFINITY) {
      const float w = __expf(mi - M);
      L += w * mlp[((size_t)p * (NCH * 2) + c) * 2 + 1];
      O += w * opart[((size_t)p * (NCH * 2) + c) * HD + d];
    }
  }
  ow[(size_t)p * HD + d] = O / L;
}

// ---------------- sum GEMM partials ----------------
__global__ __launch_bounds__(256)
void sum_partials(const float* __restrict__ part, float* __restrict__ out,
                  const int total4, const int nseg, const int stride) {
  const int i = blockIdx.x * 256 + threadIdx.x;
  if (i >= total4) return;
  float4 s = make_float4(0.f, 0.f, 0.f, 0.f);
  for (int g = 0; g < nseg; ++g) {
    const float4 v = *(const float4*)(part + (size_t)g * stride + (size_t)i * 4);
    s.x += v.x; s.y += v.y; s.z += v.z; s.w += v.w;
  }
  *(float4*)(out + (size_t)i * 4) = s;
}

extern "C" void kernel_launch(void* const* d_in, const int* in_sizes, int n_in,
                              void* d_out, int out_size, void* d_ws, size_t ws_size,
                              hipStream_t stream) {
  const float* x    = (const float*)d_in[0];
  const float* ck   = (const float*)d_in[1];
  const float* cv   = (const float*)d_in[2];
  const float* wqkv = (const float*)d_in[3];
  const float* wo   = (const float*)d_in[4];
  const int*   ctx  = (const int*)d_in[5];

  float* ws    = (float*)d_ws;
  float* pqkv  = ws;                                       // 32*32*6144
  float* qw    = pqkv + (size_t)NSEG * BATCH * QKVN;       // 32*4096
  float* kn    = qw + (size_t)BATCH * DIM;                 // 32*1024
  float* vn    = kn + (size_t)BATCH * NKV * HD;            // 32*1024
  float* opart = vn + (size_t)BATCH * NKV * HD;            // 1024*16*128
  float* mlp   = opart + (size_t)1024 * (NCH * 2) * HD;    // 1024*16*2
  float* ow    = mlp + (size_t)1024 * (NCH * 2) * 2;       // 32*4096
  float* pout  = pqkv;                                     // reuse (dead after qkv_combine)

  gemm_partial<<<dim3(QKVN / GN, NSEG), 256, 0, stream>>>(x, wqkv, pqkv, QKVN);
  qkv_combine<<<dim3(BATCH * QKVN / 2 / 256), 256, 0, stream>>>(pqkv, ctx, qw, kn, vn);
  attn_partial<<<dim3(BATCH * NKV, NCH), 256, 0, stream>>>(qw, kn, vn, ck, cv, ctx, opart, mlp);
  attn_combine<<<dim3(BATCH * NHEAD), HD, 0, stream>>>(opart, mlp, ow);
  gemm_partial<<<dim3(DIM / GN, NSEG), 256, 0, stream>>>(ow, wo, pout, DIM);
  sum_partials<<<dim3((BATCH * DIM / 4 + 255) / 256), 256, 0, stream>>>(
      pout, (float*)d_out, BATCH * DIM / 4, NSEG, BATCH * DIM);
}

// Round 2
// 309.906 us; speedup vs baseline: 1.0503x; 1.0503x over previous
//
#include <hip/hip_runtime.h>
#include <math.h>

#define BATCH 32
#define DIM   4096
#define CLEN  4096
#define HD    128
#define NKV   8
#define NHEAD 32
#define QKVN  6144          // (32 + 2*8) * 128
#define GN    64            // N per gemm block
#define KSEG  128           // K per gemm stage
#define KSTG  4             // stages per block
#define KTOT  512           // KSEG*KSTG
#define NSEG  8             // 4096 / 512
#define NCH   16            // chunks per (b,g)
#define TC    256           // rows per wave-chunk
#define NSLOT 32            // NCH * 2 halves
#define MNEG  -1.0e30f

// ---------------- helpers ----------------
template <int CTRL>
__device__ __forceinline__ float dpp_add(float x) {
  int y = __builtin_amdgcn_update_dpp(0, __float_as_int(x), CTRL, 0xF, 0xF, true);
  return x + __int_as_float(y);
}

// sum across the 32 lanes of each half-wave
__device__ __forceinline__ float half_reduce(float s) {
  s = dpp_add<0xB1>(s);    // quad_perm xor1
  s = dpp_add<0x4E>(s);    // quad_perm xor2
  s = dpp_add<0x124>(s);   // row_ror:4
  s = dpp_add<0x128>(s);   // row_ror:8
  s += __int_as_float(__builtin_amdgcn_ds_swizzle(__float_as_int(s), 0x401F)); // xor16
  return s;
}

// ---------------- skinny GEMM partial: part[seg][b][n] = sum_{k in seg} X[b][k]*W[n][k]
__global__ __launch_bounds__(256)
void gemm_partial(const float* __restrict__ X, const float* __restrict__ W,
                  float* __restrict__ part, const int N) {
  __shared__ float xs[KSEG][BATCH + 4];   // [k][b]
  __shared__ float wl[KSEG][GN + 4];      // [k][n]
  const int tid = threadIdx.x;
  const int n0  = blockIdx.x * GN;
  const int k00 = blockIdx.y * KTOT;
  const int c = tid & 31;      // float4 column along k
  const int r = tid >> 5;      // 0..7
  const int bq = (tid & 7) << 2;
  const int nq = (tid >> 3) << 1;
  float a00=0,a01=0, a10=0,a11=0, a20=0,a21=0, a30=0,a31=0;

  for (int kk = 0; kk < KSTG; ++kk) {
    const int k0 = k00 + kk * KSEG;
    if (kk) __syncthreads();
#pragma unroll
    for (int p = 0; p < 4; ++p) {
      const int b = p * 8 + r;
      const float4 v = *(const float4*)(X + (size_t)b * DIM + k0 + c * 4);
      const int k = c * 4;
      xs[k][b] = v.x; xs[k + 1][b] = v.y; xs[k + 2][b] = v.z; xs[k + 3][b] = v.w;
    }
#pragma unroll
    for (int p = 0; p < 8; ++p) {
      const int n = p * 8 + r;
      const float4 v = *(const float4*)(W + (size_t)(n0 + n) * DIM + k0 + c * 4);
      const int k = c * 4;
      wl[k][n] = v.x; wl[k + 1][n] = v.y; wl[k + 2][n] = v.z; wl[k + 3][n] = v.w;
    }
    __syncthreads();
#pragma unroll 8
    for (int k = 0; k < KSEG; ++k) {
      const float4 xv = *(const float4*)&xs[k][bq];
      const float2 wv = *(const float2*)&wl[k][nq];
      a00 += xv.x * wv.x; a01 += xv.x * wv.y;
      a10 += xv.y * wv.x; a11 += xv.y * wv.y;
      a20 += xv.z * wv.x; a21 += xv.z * wv.y;
      a30 += xv.w * wv.x; a31 += xv.w * wv.y;
    }
  }
  float* base = part + ((size_t)blockIdx.y * BATCH + bq) * N + n0 + nq;
  *(float2*)(base)         = make_float2(a00, a01);
  *(float2*)(base + N)     = make_float2(a10, a11);
  *(float2*)(base + 2 * N) = make_float2(a20, a21);
  *(float2*)(base + 3 * N) = make_float2(a30, a31);
}

// ---------------- qkv combine + RoPE ----------------
__global__ __launch_bounds__(256)
void qkv_combine(const float* __restrict__ part, const int* __restrict__ ctxp,
                 float* __restrict__ qw, float* __restrict__ kn, float* __restrict__ vn) {
  const int idx = blockIdx.x * 256 + threadIdx.x;  // pair index: 32*3072
  const int b  = idx / (QKVN / 2);
  const int c  = idx % (QKVN / 2);
  const int n0 = c * 2;
  float v0 = 0.f, v1 = 0.f;
#pragma unroll
  for (int s = 0; s < NSEG; ++s) {
    const float2 pv = *(const float2*)(part + ((size_t)s * BATCH + b) * QKVN + n0);
    v0 += pv.x; v1 += pv.y;
  }
  const float pos = (float)ctxp[0];
  const float L2T_OVER_64 = 0.20762050593045952f;  // log2(10000)/64
  if (n0 < DIM) {
    const int i = (n0 & 127) >> 1;
    const float fr = exp2f(-(float)i * L2T_OVER_64);
    float sn, cs; sincosf(pos * fr, &sn, &cs);
    qw[(size_t)b * DIM + n0]     = v0 * cs - v1 * sn;
    qw[(size_t)b * DIM + n0 + 1] = v0 * sn + v1 * cs;
  } else if (n0 < DIM + NKV * HD) {
    const int nk = n0 - DIM;
    const int i = (nk & 127) >> 1;
    const float fr = exp2f(-(float)i * L2T_OVER_64);
    float sn, cs; sincosf(pos * fr, &sn, &cs);
    kn[(size_t)b * (NKV * HD) + nk]     = v0 * cs - v1 * sn;
    kn[(size_t)b * (NKV * HD) + nk + 1] = v0 * sn + v1 * cs;
  } else {
    const int nv = n0 - DIM - NKV * HD;
    vn[(size_t)b * (NKV * HD) + nv]     = v0;
    vn[(size_t)b * (NKV * HD) + nv + 1] = v1;
  }
}

// ---------------- flash-decode partial: 1 wave = 1 chunk of 256 rows, all 4 GQA heads
__global__ __launch_bounds__(256, 4)
void attn_fd(const float* __restrict__ qw, const float* __restrict__ knew,
             const float* __restrict__ vnew, const float* __restrict__ ck,
             const float* __restrict__ cv, const int* __restrict__ ctxp,
             float* __restrict__ opart, float* __restrict__ mlp) {
  const int bg   = blockIdx.x;         // b*8 + g
  const int b = bg >> 3, g = bg & 7;
  const int wid  = threadIdx.x >> 6;
  const int lane = threadIdx.x & 63;
  const int half = lane >> 5;
  const int d4   = (lane & 31) << 2;
  const int cidx = blockIdx.y * 4 + wid;   // 0..15
  const int T    = ctxp[0] + 1;
  const int ctx  = T - 1;
  const int c0   = cidx * TC;

  const float sc = 0.08838834764831845f;   // 1/sqrt(128)
  float4 q[4];
#pragma unroll
  for (int hh = 0; hh < 4; ++hh) {
    q[hh] = *(const float4*)(qw + ((size_t)b * NHEAD + g * 4 + hh) * HD + d4);
    q[hh].x *= sc; q[hh].y *= sc; q[hh].z *= sc; q[hh].w *= sc;
  }
  const float* ckb = ck + ((size_t)b * CLEN * NKV + g) * HD + d4;
  const float* cvb = cv + ((size_t)b * CLEN * NKV + g) * HD + d4;
  const float* knr = knew + ((size_t)b * NKV + g) * HD + d4;
  const float* vnr = vnew + ((size_t)b * NKV + g) * HD + d4;

  float m[4] = {MNEG, MNEG, MNEG, MNEG};
  float l[4] = {0.f, 0.f, 0.f, 0.f};
  float4 acc[4] = {};

  for (int it = 0; it < TC / 8; ++it) {
    const int t0 = c0 + it * 8;
    float4 kb[4], vb[4];
#pragma unroll
    for (int u = 0; u < 4; ++u) {
      const int tr = t0 + u * 2 + half;
      const float* kp = (tr == ctx) ? knr : (ckb + (size_t)tr * (NKV * HD));
      const float* vp = (tr == ctx) ? vnr : (cvb + (size_t)tr * (NKV * HD));
      kb[u] = *(const float4*)kp;
      vb[u] = *(const float4*)vp;
    }
#pragma unroll
    for (int u = 0; u < 4; ++u) {
      const int tr = t0 + u * 2 + half;
      float s[4];
#pragma unroll
      for (int hh = 0; hh < 4; ++hh) {
        float d = kb[u].x * q[hh].x + kb[u].y * q[hh].y
                + kb[u].z * q[hh].z + kb[u].w * q[hh].w;
        s[hh] = half_reduce(d);
      }
      if (tr >= T) { s[0] = MNEG * 2.f; s[1] = MNEG * 2.f; s[2] = MNEG * 2.f; s[3] = MNEG * 2.f; }
      const bool grow = (s[0] > m[0]) | (s[1] > m[1]) | (s[2] > m[2]) | (s[3] > m[3]);
      if (grow) {
#pragma unroll
        for (int hh = 0; hh < 4; ++hh) {
          const float mn = fmaxf(m[hh], s[hh]);
          const float rs = __expf(m[hh] - mn);
          l[hh] *= rs;
          acc[hh].x *= rs; acc[hh].y *= rs; acc[hh].z *= rs; acc[hh].w *= rs;
          m[hh] = mn;
        }
      }
#pragma unroll
      for (int hh = 0; hh < 4; ++hh) {
        const float p = __expf(s[hh] - m[hh]);
        l[hh] += p;
        acc[hh].x += p * vb[u].x; acc[hh].y += p * vb[u].y;
        acc[hh].z += p * vb[u].z; acc[hh].w += p * vb[u].w;
      }
    }
  }

#pragma unroll
  for (int hh = 0; hh < 4; ++hh) {
    const int hid = b * NHEAD + g * 4 + hh;
    const size_t slot = (size_t)hid * NSLOT + cidx * 2 + half;
    *(float4*)(opart + slot * HD + d4) = acc[hh];
    if ((lane & 31) == 0) { mlp[slot * 2] = m[hh]; mlp[slot * 2 + 1] = l[hh]; }
  }
}

// ---------------- flash combine ----------------
__global__ __launch_bounds__(128)
void attn_combine(const float* __restrict__ opart, const float* __restrict__ mlp,
                  float* __restrict__ ow) {
  const int p = blockIdx.x;      // 0..1023 = b*32 + g*4 + h
  const int d = threadIdx.x;     // 0..127
  float M = MNEG;
#pragma unroll
  for (int c = 0; c < NSLOT; ++c) M = fmaxf(M, mlp[((size_t)p * NSLOT + c) * 2]);
  float L = 0.f, O = 0.f;
#pragma unroll 8
  for (int c = 0; c < NSLOT; ++c) {
    const float mi = mlp[((size_t)p * NSLOT + c) * 2];
    const float w = __expf(mi - M);
    L += w * mlp[((size_t)p * NSLOT + c) * 2 + 1];
    O += w * opart[((size_t)p * NSLOT + c) * HD + d];
  }
  ow[(size_t)p * HD + d] = O / L;
}

// ---------------- sum GEMM partials ----------------
__global__ __launch_bounds__(256)
void sum_partials(const float* __restrict__ part, float* __restrict__ out,
                  const int total4, const int nseg, const int stride) {
  const int i = blockIdx.x * 256 + threadIdx.x;
  if (i >= total4) return;
  float4 s = make_float4(0.f, 0.f, 0.f, 0.f);
  for (int g = 0; g < nseg; ++g) {
    const float4 v = *(const float4*)(part + (size_t)g * stride + (size_t)i * 4);
    s.x += v.x; s.y += v.y; s.z += v.z; s.w += v.w;
  }
  *(float4*)(out + (size_t)i * 4) = s;
}

extern "C" void kernel_launch(void* const* d_in, const int* in_sizes, int n_in,
                              void* d_out, int out_size, void* d_ws, size_t ws_size,
                              hipStream_t stream) {
  const float* x    = (const float*)d_in[0];
  const float* ck   = (const float*)d_in[1];
  const float* cv   = (const float*)d_in[2];
  const float* wqkv = (const float*)d_in[3];
  const float* wo   = (const float*)d_in[4];
  const int*   ctx  = (const int*)d_in[5];

  float* ws    = (float*)d_ws;
  float* pqkv  = ws;                                        // 8*32*6144
  float* qw    = pqkv + (size_t)NSEG * BATCH * QKVN;        // 32*4096
  float* kn    = qw + (size_t)BATCH * DIM;                  // 32*1024
  float* vn    = kn + (size_t)BATCH * NKV * HD;             // 32*1024
  float* opart = vn + (size_t)BATCH * NKV * HD;             // 1024*32*128
  float* mlp   = opart + (size_t)1024 * NSLOT * HD;         // 1024*32*2
  float* ow    = mlp + (size_t)1024 * NSLOT * 2;            // 32*4096
  float* pout  = pqkv;                                      // reuse (dead after qkv_combine)

  gemm_partial<<<dim3(QKVN / GN, NSEG), 256, 0, stream>>>(x, wqkv, pqkv, QKVN);
  qkv_combine<<<dim3(BATCH * QKVN / 2 / 256), 256, 0, stream>>>(pqkv, ctx, qw, kn, vn);
  attn_fd<<<dim3(BATCH * NKV, NCH / 4), 256, 0, stream>>>(qw, kn, vn, ck, cv, ctx, opart, mlp);
  attn_combine<<<dim3(BATCH * NHEAD), HD, 0, stream>>>(opart, mlp, ow);
  gemm_partial<<<dim3(DIM / GN, NSEG), 256, 0, stream>>>(ow, wo, pout, DIM);
  sum_partials<<<dim3((BATCH * DIM / 4 + 255) / 256), 256, 0, stream>>>(
      pout, (float*)d_out, BATCH * DIM / 4, NSEG, BATCH * DIM);
}

// Round 3
// 269.708 us; speedup vs baseline: 1.2069x; 1.1490x over previous
//
#include <hip/hip_runtime.h>
#include <math.h>

#define BATCH 32
#define DIM   4096
#define CLEN  4096
#define HD    128
#define NKV   8
#define NHEAD 32
#define QKVN  6144          // (32 + 2*8) * 128
#define KVSTR (NKV * HD)    // 1024 floats between consecutive t rows
#define GN    64            // N per gemm block
#define KSEG  128           // K per gemm stage
#define KSTG  4             // stages per block
#define KTOT  512           // KSEG*KSTG
#define NSEG  8             // 4096 / 512
#define NCH   16            // chunks per (b,g)
#define TC    256           // rows per wave-chunk
#define NSLOT 16            // one slot per chunk (halves merged in-kernel)
#define MNEG  -1.0e30f
#define SMASK -3.0e38f

// ---------------- helpers ----------------
template <int CTRL>
__device__ __forceinline__ float dpp_add(float x) {
  int y = __builtin_amdgcn_update_dpp(0, __float_as_int(x), CTRL, 0xF, 0xF, true);
  return x + __int_as_float(y);
}

// sum across the 32 lanes of each half-wave
__device__ __forceinline__ float half_reduce(float s) {
  s = dpp_add<0xB1>(s);    // quad_perm xor1
  s = dpp_add<0x4E>(s);    // quad_perm xor2
  s = dpp_add<0x124>(s);   // row_ror:4
  s = dpp_add<0x128>(s);   // row_ror:8
  s += __int_as_float(__builtin_amdgcn_ds_swizzle(__float_as_int(s), 0x401F)); // xor16
  return s;
}

__device__ __forceinline__ float xhalf32(float v, int lane) {
  return __int_as_float(__builtin_amdgcn_ds_bpermute((lane ^ 32) << 2, __float_as_int(v)));
}

// ---------------- skinny GEMM partial: part[seg][b][n] = sum_{k in seg} X[b][k]*W[n][k]
// LDS layouts: xs[k][32] / wl[k][64], quad-XOR swizzled: physquad = quad ^ ((k>>2)&7)
__global__ __launch_bounds__(256)
void gemm_partial(const float* __restrict__ X, const float* __restrict__ W,
                  float* __restrict__ part, const int N) {
  __shared__ float xs[KSEG * 32];
  __shared__ float wl[KSEG * 64];
  const int tid = threadIdx.x;
  const int c   = tid & 31;        // k-quad index
  const int r   = tid >> 5;        // 0..7
  const int cx7 = c & 7;
  const int n0  = blockIdx.x * GN;
  const int k00 = blockIdx.y * KTOT;
  const int bq8 = tid & 7;         // b-quad for compute
  const int tq  = tid >> 3;        // 0..31
  const int nqq = tq >> 1;         // n-quad 0..15
  const int nqo = (tq & 1) << 1;   // 0 or 2

  float a00=0,a01=0, a10=0,a11=0, a20=0,a21=0, a30=0,a31=0;

  float* xwp  = xs + (c * 4) * 32 + ((r ^ cx7) << 2);
  float* wwp0 = wl + (c * 4) * 64 + ((r ^ cx7) << 2);
  float* wwp1 = wwp0 + 32;         // physquad p=1 -> +8 quads

  for (int kk = 0; kk < KSTG; ++kk) {
    const int k0 = k00 + kk * KSEG;
    // ---- issue global loads early (overlap previous stage's compute) ----
    const float* Xp = X + (size_t)(r * 4) * DIM + k0 + c * 4;
    const float4 xv0 = *(const float4*)(Xp);
    const float4 xv1 = *(const float4*)(Xp + DIM);
    const float4 xv2 = *(const float4*)(Xp + 2 * DIM);
    const float4 xv3 = *(const float4*)(Xp + 3 * DIM);
    const float* Wp0 = W + (size_t)(n0 + r * 4) * DIM + k0 + c * 4;
    const float4 wv00 = *(const float4*)(Wp0);
    const float4 wv01 = *(const float4*)(Wp0 + DIM);
    const float4 wv02 = *(const float4*)(Wp0 + 2 * DIM);
    const float4 wv03 = *(const float4*)(Wp0 + 3 * DIM);
    const float* Wp1 = Wp0 + (size_t)32 * DIM;
    const float4 wv10 = *(const float4*)(Wp1);
    const float4 wv11 = *(const float4*)(Wp1 + DIM);
    const float4 wv12 = *(const float4*)(Wp1 + 2 * DIM);
    const float4 wv13 = *(const float4*)(Wp1 + 3 * DIM);

    if (kk) __syncthreads();       // previous compute done before LDS overwrite

    // ---- register 4x4 transpose -> b128 LDS writes (4-way max) ----
    *(float4*)(xwp + 0)   = make_float4(xv0.x, xv1.x, xv2.x, xv3.x);
    *(float4*)(xwp + 32)  = make_float4(xv0.y, xv1.y, xv2.y, xv3.y);
    *(float4*)(xwp + 64)  = make_float4(xv0.z, xv1.z, xv2.z, xv3.z);
    *(float4*)(xwp + 96)  = make_float4(xv0.w, xv1.w, xv2.w, xv3.w);
    *(float4*)(wwp0 + 0)   = make_float4(wv00.x, wv01.x, wv02.x, wv03.x);
    *(float4*)(wwp0 + 64)  = make_float4(wv00.y, wv01.y, wv02.y, wv03.y);
    *(float4*)(wwp0 + 128) = make_float4(wv00.z, wv01.z, wv02.z, wv03.z);
    *(float4*)(wwp0 + 192) = make_float4(wv00.w, wv01.w, wv02.w, wv03.w);
    *(float4*)(wwp1 + 0)   = make_float4(wv10.x, wv11.x, wv12.x, wv13.x);
    *(float4*)(wwp1 + 64)  = make_float4(wv10.y, wv11.y, wv12.y, wv13.y);
    *(float4*)(wwp1 + 128) = make_float4(wv10.z, wv11.z, wv12.z, wv13.z);
    *(float4*)(wwp1 + 192) = make_float4(wv10.w, wv11.w, wv12.w, wv13.w);
    __syncthreads();

    // ---- compute: g = (k>>2)&7 constant per unrolled body ----
#pragma unroll 8
    for (int k2 = 0; k2 < KSEG / 4; ++k2) {
      const int g = k2 & 7;
      const float* xr = xs + (k2 * 4) * 32 + ((bq8 ^ g) << 2);
      const float* wr = wl + (k2 * 4) * 64 + ((nqq ^ g) << 2) + nqo;
#pragma unroll
      for (int j = 0; j < 4; ++j) {
        const float4 xv = *(const float4*)(xr + j * 32);
        const float2 wv = *(const float2*)(wr + j * 64);
        a00 = fmaf(xv.x, wv.x, a00); a01 = fmaf(xv.x, wv.y, a01);
        a10 = fmaf(xv.y, wv.x, a10); a11 = fmaf(xv.y, wv.y, a11);
        a20 = fmaf(xv.z, wv.x, a20); a21 = fmaf(xv.z, wv.y, a21);
        a30 = fmaf(xv.w, wv.x, a30); a31 = fmaf(xv.w, wv.y, a31);
      }
    }
  }
  const int bq = bq8 << 2;
  const int nq = tq << 1;
  float* base = part + ((size_t)blockIdx.y * BATCH + bq) * N + n0 + nq;
  *(float2*)(base)         = make_float2(a00, a01);
  *(float2*)(base + N)     = make_float2(a10, a11);
  *(float2*)(base + 2 * N) = make_float2(a20, a21);
  *(float2*)(base + 3 * N) = make_float2(a30, a31);
}

// ---------------- qkv combine + RoPE ----------------
__global__ __launch_bounds__(256)
void qkv_combine(const float* __restrict__ part, const int* __restrict__ ctxp,
                 float* __restrict__ qw, float* __restrict__ kn, float* __restrict__ vn) {
  const int idx = blockIdx.x * 256 + threadIdx.x;  // pair index: 32*3072
  const int b  = idx / (QKVN / 2);
  const int c  = idx % (QKVN / 2);
  const int n0 = c * 2;
  float v0 = 0.f, v1 = 0.f;
#pragma unroll
  for (int s = 0; s < NSEG; ++s) {
    const float2 pv = *(const float2*)(part + ((size_t)s * BATCH + b) * QKVN + n0);
    v0 += pv.x; v1 += pv.y;
  }
  const float pos = (float)ctxp[0];
  const float L2T_OVER_64 = 0.20762050593045952f;  // log2(10000)/64
  if (n0 < DIM) {
    const int i = (n0 & 127) >> 1;
    const float fr = exp2f(-(float)i * L2T_OVER_64);
    float sn, cs; sincosf(pos * fr, &sn, &cs);
    qw[(size_t)b * DIM + n0]     = v0 * cs - v1 * sn;
    qw[(size_t)b * DIM + n0 + 1] = v0 * sn + v1 * cs;
  } else if (n0 < DIM + NKV * HD) {
    const int nk = n0 - DIM;
    const int i = (nk & 127) >> 1;
    const float fr = exp2f(-(float)i * L2T_OVER_64);
    float sn, cs; sincosf(pos * fr, &sn, &cs);
    kn[(size_t)b * (NKV * HD) + nk]     = v0 * cs - v1 * sn;
    kn[(size_t)b * (NKV * HD) + nk + 1] = v0 * sn + v1 * cs;
  } else {
    const int nv = n0 - DIM - NKV * HD;
    vn[(size_t)b * (NKV * HD) + nv]     = v0;
    vn[(size_t)b * (NKV * HD) + nv + 1] = v1;
  }
}

// ---------------- flash-decode: ping-pong prefetch, 4 GQA heads per wave ----------------
__device__ __forceinline__ void load8(float4 kb[4], float4 vb[4],
    const float* __restrict__ ckb, const float* __restrict__ cvb,
    const float* __restrict__ knr, const float* __restrict__ vnr,
    const int t0, const int half, const int ctx, const bool edge) {
#pragma unroll
  for (int u = 0; u < 4; ++u) {
    const int tr = t0 + u * 2 + half;
    const float* kp = ckb + (size_t)tr * KVSTR;
    const float* vp = cvb + (size_t)tr * KVSTR;
    if (edge) {                       // wave-uniform branch
      if (tr == ctx) { kp = knr; vp = vnr; }
    }
    kb[u] = *(const float4*)kp;
    vb[u] = *(const float4*)vp;
  }
}

__device__ __forceinline__ void compute8(const float4 kb[4], const float4 vb[4],
    const float4 q[4], const int t0, const int half, const int ctx, const bool edge,
    float m[4], float l[4], float4 acc[4]) {
#pragma unroll
  for (int u = 0; u < 4; ++u) {
    float s[4];
#pragma unroll
    for (int hh = 0; hh < 4; ++hh) {
      float d = fmaf(kb[u].x, q[hh].x, kb[u].y * q[hh].y);
      d = fmaf(kb[u].z, q[hh].z, d);
      d = fmaf(kb[u].w, q[hh].w, d);
      s[hh] = half_reduce(d);
    }
    if (edge) {                       // wave-uniform branch
      const int tr = t0 + u * 2 + half;
      if (tr > ctx) { s[0] = SMASK; s[1] = SMASK; s[2] = SMASK; s[3] = SMASK; }
    }
    if ((s[0] > m[0]) | (s[1] > m[1]) | (s[2] > m[2]) | (s[3] > m[3])) {
#pragma unroll
      for (int hh = 0; hh < 4; ++hh) {
        const float mn = fmaxf(m[hh], s[hh]);
        const float rs = __expf(m[hh] - mn);
        l[hh] *= rs;
        acc[hh].x *= rs; acc[hh].y *= rs; acc[hh].z *= rs; acc[hh].w *= rs;
        m[hh] = mn;
      }
    }
#pragma unroll
    for (int hh = 0; hh < 4; ++hh) {
      const float p = __expf(s[hh] - m[hh]);
      l[hh] += p;
      acc[hh].x = fmaf(p, vb[u].x, acc[hh].x);
      acc[hh].y = fmaf(p, vb[u].y, acc[hh].y);
      acc[hh].z = fmaf(p, vb[u].z, acc[hh].z);
      acc[hh].w = fmaf(p, vb[u].w, acc[hh].w);
    }
  }
}

__global__ __launch_bounds__(256)
void attn_fd(const float* __restrict__ qw, const float* __restrict__ knew,
             const float* __restrict__ vnew, const float* __restrict__ ck,
             const float* __restrict__ cv, const int* __restrict__ ctxp,
             float* __restrict__ opart, float* __restrict__ mlp) {
  const int bg   = blockIdx.x;         // b*8 + g
  const int b = bg >> 3, g = bg & 7;
  const int wid  = threadIdx.x >> 6;
  const int lane = threadIdx.x & 63;
  const int half = lane >> 5;
  const int d4   = (lane & 31) << 2;
  const int cidx = blockIdx.y * 4 + wid;   // 0..15
  const int ctx  = ctxp[0];
  const int c0   = cidx * TC;

  const float sc = 0.08838834764831845f;   // 1/sqrt(128)
  float4 q[4];
#pragma unroll
  for (int hh = 0; hh < 4; ++hh) {
    q[hh] = *(const float4*)(qw + ((size_t)b * NHEAD + g * 4 + hh) * HD + d4);
    q[hh].x *= sc; q[hh].y *= sc; q[hh].z *= sc; q[hh].w *= sc;
  }
  const float* ckb = ck + ((size_t)b * CLEN * NKV + g) * HD + d4;
  const float* cvb = cv + ((size_t)b * CLEN * NKV + g) * HD + d4;
  const float* knr = knew + ((size_t)b * NKV + g) * HD + d4;
  const float* vnr = vnew + ((size_t)b * NKV + g) * HD + d4;

  float m[4] = {MNEG, MNEG, MNEG, MNEG};
  float l[4] = {0.f, 0.f, 0.f, 0.f};
  float4 acc[4] = {};

  float4 ka[4], va[4], kb2[4], vb2[4];
  int t = c0;
  load8(ka, va, ckb, cvb, knr, vnr, t, half, ctx, t + 8 > ctx);
  for (int it = 0; it < TC / 16; ++it) {
    const int tb = t + 8;
    load8(kb2, vb2, ckb, cvb, knr, vnr, tb, half, ctx, tb + 8 > ctx);
    compute8(ka, va, q, t, half, ctx, t + 8 > ctx, m, l, acc);
    const int tn = t + 16;
    if (it + 1 < TC / 16)
      load8(ka, va, ckb, cvb, knr, vnr, tn, half, ctx, tn + 8 > ctx);
    compute8(kb2, vb2, q, tb, half, ctx, tb + 8 > ctx, m, l, acc);
    t = tn;
  }

  // ---- merge the two half-wave states (ds_bpermute lane^32) ----
#pragma unroll
  for (int hh = 0; hh < 4; ++hh) {
    const float mo = xhalf32(m[hh], lane);
    const float lo = xhalf32(l[hh], lane);
    float4 ao;
    ao.x = xhalf32(acc[hh].x, lane); ao.y = xhalf32(acc[hh].y, lane);
    ao.z = xhalf32(acc[hh].z, lane); ao.w = xhalf32(acc[hh].w, lane);
    const float mc = fmaxf(m[hh], mo);
    const float wa = __expf(m[hh] - mc);
    const float wb = __expf(mo - mc);
    l[hh] = wa * l[hh] + wb * lo;
    acc[hh].x = wa * acc[hh].x + wb * ao.x;
    acc[hh].y = wa * acc[hh].y + wb * ao.y;
    acc[hh].z = wa * acc[hh].z + wb * ao.z;
    acc[hh].w = wa * acc[hh].w + wb * ao.w;
    m[hh] = mc;
  }
  if (half == 0) {
#pragma unroll
    for (int hh = 0; hh < 4; ++hh) {
      const int hid = b * NHEAD + g * 4 + hh;
      const size_t slot = (size_t)hid * NSLOT + cidx;
      *(float4*)(opart + slot * HD + d4) = acc[hh];
      if ((lane & 31) == 0) { mlp[slot * 2] = m[hh]; mlp[slot * 2 + 1] = l[hh]; }
    }
  }
}

// ---------------- flash combine ----------------
__global__ __launch_bounds__(128)
void attn_combine(const float* __restrict__ opart, const float* __restrict__ mlp,
                  float* __restrict__ ow) {
  const int p = blockIdx.x;      // 0..1023 = b*32 + g*4 + h
  const int d = threadIdx.x;     // 0..127
  float M = MNEG;
#pragma unroll
  for (int c = 0; c < NSLOT; ++c) M = fmaxf(M, mlp[((size_t)p * NSLOT + c) * 2]);
  float L = 0.f, O = 0.f;
#pragma unroll 8
  for (int c = 0; c < NSLOT; ++c) {
    const float mi = mlp[((size_t)p * NSLOT + c) * 2];
    const float w = __expf(mi - M);
    L += w * mlp[((size_t)p * NSLOT + c) * 2 + 1];
    O += w * opart[((size_t)p * NSLOT + c) * HD + d];
  }
  ow[(size_t)p * HD + d] = O / L;
}

// ---------------- sum GEMM partials ----------------
__global__ __launch_bounds__(256)
void sum_partials(const float* __restrict__ part, float* __restrict__ out,
                  const int total4, const int nseg, const int stride) {
  const int i = blockIdx.x * 256 + threadIdx.x;
  if (i >= total4) return;
  float4 s = make_float4(0.f, 0.f, 0.f, 0.f);
  for (int g = 0; g < nseg; ++g) {
    const float4 v = *(const float4*)(part + (size_t)g * stride + (size_t)i * 4);
    s.x += v.x; s.y += v.y; s.z += v.z; s.w += v.w;
  }
  *(float4*)(out + (size_t)i * 4) = s;
}

extern "C" void kernel_launch(void* const* d_in, const int* in_sizes, int n_in,
                              void* d_out, int out_size, void* d_ws, size_t ws_size,
                              hipStream_t stream) {
  const float* x    = (const float*)d_in[0];
  const float* ck   = (const float*)d_in[1];
  const float* cv   = (const float*)d_in[2];
  const float* wqkv = (const float*)d_in[3];
  const float* wo   = (const float*)d_in[4];
  const int*   ctx  = (const int*)d_in[5];

  float* ws    = (float*)d_ws;
  float* pqkv  = ws;                                        // 8*32*6144
  float* qw    = pqkv + (size_t)NSEG * BATCH * QKVN;        // 32*4096
  float* kn    = qw + (size_t)BATCH * DIM;                  // 32*1024
  float* vn    = kn + (size_t)BATCH * NKV * HD;             // 32*1024
  float* opart = vn + (size_t)BATCH * NKV * HD;             // 1024*16*128
  float* mlp   = opart + (size_t)1024 * NSLOT * HD;         // 1024*16*2
  float* ow    = mlp + (size_t)1024 * NSLOT * 2;            // 32*4096
  float* pout  = pqkv;                                      // reuse (dead after qkv_combine)

  gemm_partial<<<dim3(QKVN / GN, NSEG), 256, 0, stream>>>(x, wqkv, pqkv, QKVN);
  qkv_combine<<<dim3(BATCH * QKVN / 2 / 256), 256, 0, stream>>>(pqkv, ctx, qw, kn, vn);
  attn_fd<<<dim3(BATCH * NKV, NCH / 4), 256, 0, stream>>>(qw, kn, vn, ck, cv, ctx, opart, mlp);
  attn_combine<<<dim3(BATCH * NHEAD), HD, 0, stream>>>(opart, mlp, ow);
  gemm_partial<<<dim3(DIM / GN, NSEG), 256, 0, stream>>>(ow, wo, pout, DIM);
  sum_partials<<<dim3((BATCH * DIM / 4 + 255) / 256), 256, 0, stream>>>(
      pout, (float*)d_out, BATCH * DIM / 4, NSEG, BATCH * DIM);
}